// Round 1
// baseline (516.876 us; speedup 1.0000x reference)
//
#include <hip/hip_runtime.h>
#include <math.h>

#define H 4
#define HD 64
#define NN 1024
#define BB 8
#define FIN 256
#define FOUT 256

// ---------------------------------------------------------------------------
// Kernel A: h = x @ W, output written in [b][head][n][d] layout (fp32).
// 64x64 output tile per block, K staged through LDS in 64-chunks.
// ---------------------------------------------------------------------------
__global__ __launch_bounds__(256) void gemm_xw(const float* __restrict__ x,
                                               const float* __restrict__ W,
                                               float* __restrict__ h_ws) {
  __shared__ float xs[64][68];   // stride 68 keeps float4 alignment, breaks bank aliasing
  __shared__ float ws_[64][68];
  const int tid = threadIdx.x;
  const int tx = tid & 15, ty = tid >> 4;
  const int bn0 = blockIdx.x * 64;
  const int f0 = blockIdx.y * 64;
  float c[4][4] = {};

  for (int k0 = 0; k0 < FIN; k0 += 64) {
    {
      int row = tid >> 4;
      int col = (tid & 15) * 4;
#pragma unroll
      for (int p = 0; p < 4; ++p) {
        int r = p * 16 + row;
        float4 xv = *(const float4*)&x[(size_t)(bn0 + r) * FIN + k0 + col];
        float4 wv = *(const float4*)&W[(size_t)(k0 + r) * FOUT + f0 + col];
        *(float4*)&xs[r][col] = xv;
        *(float4*)&ws_[r][col] = wv;
      }
    }
    __syncthreads();
#pragma unroll
    for (int kk = 0; kk < 64; kk += 4) {
      float4 a_[4], b_[4];
#pragma unroll
      for (int i = 0; i < 4; ++i) a_[i] = *(float4*)&xs[ty * 4 + i][kk];
#pragma unroll
      for (int k = 0; k < 4; ++k) b_[k] = *(float4*)&ws_[kk + k][tx * 4];
#pragma unroll
      for (int i = 0; i < 4; ++i) {
        float av[4] = {a_[i].x, a_[i].y, a_[i].z, a_[i].w};
#pragma unroll
        for (int k = 0; k < 4; ++k) {
          c[i][0] = fmaf(av[k], b_[k].x, c[i][0]);
          c[i][1] = fmaf(av[k], b_[k].y, c[i][1]);
          c[i][2] = fmaf(av[k], b_[k].z, c[i][2]);
          c[i][3] = fmaf(av[k], b_[k].w, c[i][3]);
        }
      }
    }
    __syncthreads();
  }

  // epilogue: f-tile == head (HD == 64 == tile width)
  const int b = bn0 / NN;
  const int head = blockIdx.y;
  const int nbase = (bn0 % NN) + ty * 4;
#pragma unroll
  for (int i = 0; i < 4; ++i) {
    int n = nbase + i;
    float4 v = {c[i][0], c[i][1], c[i][2], c[i][3]};
    *(float4*)&h_ws[((size_t)(b * H + head) * NN + n) * HD + tx * 4] = v;
  }
}

// ---------------------------------------------------------------------------
// Kernel B: s1[row] = h[row,:]·a1[head], s2[row] = h[row,:]·a2[head]
// One wave per row (row = (b*H+head)*N + n), lane = d.
// ---------------------------------------------------------------------------
__global__ __launch_bounds__(256) void scores(const float* __restrict__ h_ws,
                                              const float* __restrict__ a,
                                              float* __restrict__ s1_ws,
                                              float* __restrict__ s2_ws) {
  const int w = threadIdx.x >> 6;
  const int lane = threadIdx.x & 63;
  const int row = blockIdx.x * 4 + w;  // 0..32767
  const int head = (row >> 10) & (H - 1);
  float hv = h_ws[(size_t)row * HD + lane];
  float a1 = a[head * 2 * HD + lane];
  float a2 = a[head * 2 * HD + HD + lane];
  float v1 = hv * a1, v2 = hv * a2;
#pragma unroll
  for (int off = 32; off; off >>= 1) {
    v1 += __shfl_xor(v1, off);
    v2 += __shfl_xor(v2, off);
  }
  if (lane == 0) {
    s1_ws[row] = v1;
    s2_ws[row] = v2;
  }
}

// ---------------------------------------------------------------------------
// Kernel C: flash-style attention. One block per (b,h) x 64-row slab.
// 4 waves, each wave owns 16 rows. Per 64-m chunk:
//   phase1: global->reg h chunk loads (latency overlapped with phase2)
//   phase2: lane=m score compute, online softmax (wave-uniform per-row state)
//   phase3: regs->LDS h chunk
//   phase4: lane=d accumulation, p broadcast-read as float4 from LDS
// ---------------------------------------------------------------------------
__global__ __launch_bounds__(256) void attn(const float* __restrict__ h_ws,
                                            const float* __restrict__ s1_ws,
                                            const float* __restrict__ s2_ws,
                                            const int* __restrict__ adj,
                                            float* __restrict__ out) {
  __shared__ float s2_all[NN];
  __shared__ float s1_blk[64];
  __shared__ float h_chunk[64 * 64];
  __shared__ float p_tile[64 * 64];
  const int tid = threadIdx.x;
  const int lane = tid & 63;
  const int w = tid >> 6;
  const int ntile = blockIdx.x;
  const int bh = blockIdx.y;
  const int b = bh >> 2, head = bh & 3;

  {
    float4 v = *(const float4*)&s2_ws[(size_t)bh * NN + tid * 4];
    *(float4*)&s2_all[tid * 4] = v;
    if (tid < 64) s1_blk[tid] = s1_ws[(size_t)bh * NN + ntile * 64 + tid];
  }
  __syncthreads();

  float M[16], L[16], acc[16];
#pragma unroll
  for (int r = 0; r < 16; ++r) {
    M[r] = -1e30f;
    L[r] = 0.f;
    acc[r] = 0.f;
  }
  const int prow = tid >> 4, pcol = (tid & 15) * 4;

  for (int m0 = 0; m0 < NN; m0 += 64) {
    // phase1: issue global loads of h chunk
    float4 hreg[4];
#pragma unroll
    for (int p = 0; p < 4; ++p) {
      int mr = p * 16 + prow;
      hreg[p] = *(const float4*)&h_ws[((size_t)bh * NN + m0 + mr) * HD + pcol];
    }
    // adj prefetch (16 independent loads)
    int adjv[16];
#pragma unroll
    for (int r = 0; r < 16; ++r) {
      int n = ntile * 64 + w * 16 + r;
      adjv[r] = adj[((size_t)b * NN + n) * NN + m0 + lane];
    }
    float s2v = s2_all[m0 + lane];

    // phase2: scores + online softmax, lane = m
#pragma unroll
    for (int r = 0; r < 16; ++r) {
      int nl = w * 16 + r;
      float e = s1_blk[nl] + s2v;
      e = fmaxf(e, 0.2f * e);           // leaky_relu (0.2 < 1)
      e = (adjv[r] == 0) ? -1e30f : e;  // mask
      float cmax = e;
#pragma unroll
      for (int off = 32; off; off >>= 1) cmax = fmaxf(cmax, __shfl_xor(cmax, off));
      float newM = fmaxf(M[r], cmax);
      float alpha = __expf(M[r] - newM);
      float p = __expf(e - newM);
      float csum = p;
#pragma unroll
      for (int off = 32; off; off >>= 1) csum += __shfl_xor(csum, off);
      L[r] = L[r] * alpha + csum;
      acc[r] *= alpha;
      M[r] = newM;
      p_tile[nl * 64 + lane] = p;
    }

    // phase3: write h chunk to LDS
#pragma unroll
    for (int p = 0; p < 4; ++p) {
      int mr = p * 16 + prow;
      *(float4*)&h_chunk[mr * 64 + pcol] = hreg[p];
    }
    __syncthreads();

    // phase4: accumulate, lane = d
#pragma unroll
    for (int j4 = 0; j4 < 16; ++j4) {
      float h0 = h_chunk[(j4 * 4 + 0) * 64 + lane];
      float h1 = h_chunk[(j4 * 4 + 1) * 64 + lane];
      float h2 = h_chunk[(j4 * 4 + 2) * 64 + lane];
      float h3 = h_chunk[(j4 * 4 + 3) * 64 + lane];
#pragma unroll
      for (int r = 0; r < 16; ++r) {
        int nl = w * 16 + r;
        float4 pv = *(float4*)&p_tile[nl * 64 + j4 * 4];
        acc[r] = fmaf(pv.x, h0, acc[r]);
        acc[r] = fmaf(pv.y, h1, acc[r]);
        acc[r] = fmaf(pv.z, h2, acc[r]);
        acc[r] = fmaf(pv.w, h3, acc[r]);
      }
    }
    __syncthreads();
  }

  // epilogue: out[b][n][head*HD + d]
#pragma unroll
  for (int r = 0; r < 16; ++r) {
    int n = ntile * 64 + w * 16 + r;
    out[((size_t)b * NN + n) * FOUT + head * HD + lane] = acc[r] / L[r];
  }
}

extern "C" void kernel_launch(void* const* d_in, const int* in_sizes, int n_in,
                              void* d_out, int out_size, void* d_ws, size_t ws_size,
                              hipStream_t stream) {
  const float* x = (const float*)d_in[0];
  const int* adj = (const int*)d_in[1];
  const float* W = (const float*)d_in[2];
  const float* a = (const float*)d_in[3];
  float* out = (float*)d_out;

  float* h_ws = (float*)d_ws;                          // B*H*N*HD = 2M floats
  float* s1_ws = h_ws + (size_t)BB * H * NN * HD;      // 32768 floats
  float* s2_ws = s1_ws + (size_t)BB * H * NN;          // 32768 floats

  dim3 gA(128, 4);
  gemm_xw<<<gA, 256, 0, stream>>>(x, W, h_ws);
  scores<<<8192, 256, 0, stream>>>(h_ws, a, s1_ws, s2_ws);
  dim3 gC(16, 32);
  attn<<<gC, 256, 0, stream>>>(h_ws, s1_ws, s2_ws, adj, out);
}

// Round 2
// 120.927 us; speedup vs baseline: 4.2743x; 4.2743x over previous
//
#include <hip/hip_runtime.h>
#include <math.h>

#define H 4
#define HD 64
#define NN 1024
#define BB 8
#define FIN 256
#define FOUT 256

typedef _Float16 f16x8 __attribute__((ext_vector_type(8)));
typedef _Float16 f16x4 __attribute__((ext_vector_type(4)));
typedef float f32x4 __attribute__((ext_vector_type(4)));

// ---------------------------------------------------------------------------
// Kernel A: h = x @ W via fp16 MFMA (16x16x32). Block = 64 rows x 1 head.
// Outputs: hT fp16 in [bh][d][n] layout (== MFMA B-operand friendly, m-contig)
//          s1/s2 fp32 (fused scores: s1=h.a1, s2=h.a2) from fp32 accumulators.
// ---------------------------------------------------------------------------
__global__ __launch_bounds__(256) void gemm_xw(const float* __restrict__ x,
                                               const float* __restrict__ W,
                                               const float* __restrict__ a,
                                               _Float16* __restrict__ hT,
                                               float* __restrict__ s1_ws,
                                               float* __restrict__ s2_ws) {
  __shared__ _Float16 xs[64][72];   // [n][k]  stride 144B (16B-mult, 2-way banks)
  __shared__ _Float16 wst[64][72];  // [f][k]  (W transposed during staging)
  const int tid = threadIdx.x;
  const int lane = tid & 63, w = tid >> 6;
  const int c = lane & 15, q = lane >> 4;
  const int bn0 = blockIdx.x * 64;  // global row in [0, B*N)
  const int head = blockIdx.y;
  const int b = bn0 >> 10;
  const int nb = bn0 & 1023;
  const int bh = b * H + head;

  f32x4 acc[4];
#pragma unroll
  for (int t = 0; t < 4; ++t) acc[t] = (f32x4){0.f, 0.f, 0.f, 0.f};

  const int srow = tid >> 2;         // 0..63
  const int skoff = (tid & 3) * 16;  // 0,16,32,48

  for (int ch = 0; ch < 4; ++ch) {
    // stage x tile (fp32 -> fp16), row-major [n][k]
    {
      const float* xp = x + (size_t)(bn0 + srow) * FIN + ch * 64 + skoff;
      f16x8 v0, v1;
#pragma unroll
      for (int i = 0; i < 8; ++i) v0[i] = (_Float16)xp[i];
#pragma unroll
      for (int i = 0; i < 8; ++i) v1[i] = (_Float16)xp[8 + i];
      *(f16x8*)&xs[srow][skoff] = v0;
      *(f16x8*)&xs[srow][skoff + 8] = v1;
    }
    // stage W transposed: wst[f][k] <- W[k][f]
    {
      const float* wp = W + (size_t)(ch * 64 + lane) * FOUT + head * 64 + w * 16;
#pragma unroll
      for (int i = 0; i < 16; ++i) wst[w * 16 + i][lane] = (_Float16)wp[i];
    }
    __syncthreads();
#pragma unroll
    for (int ks = 0; ks < 2; ++ks) {
      f16x8 af = *(const f16x8*)&xs[w * 16 + c][ks * 32 + q * 8];
#pragma unroll
      for (int t = 0; t < 4; ++t) {
        f16x8 bf = *(const f16x8*)&wst[t * 16 + c][ks * 32 + q * 8];
        acc[t] = __builtin_amdgcn_mfma_f32_16x16x32_f16(af, bf, acc[t], 0, 0, 0);
      }
    }
    __syncthreads();
  }

  // epilogue: D-frag lane holds (n = w*16 + q*4 + rr, f_local = t*16 + c)
  float a1v[4], a2v[4];
#pragma unroll
  for (int t = 0; t < 4; ++t) {
    a1v[t] = a[head * 2 * HD + t * 16 + c];
    a2v[t] = a[head * 2 * HD + HD + t * 16 + c];
  }
  float s1p[4] = {0.f, 0.f, 0.f, 0.f};
  float s2p[4] = {0.f, 0.f, 0.f, 0.f};
#pragma unroll
  for (int t = 0; t < 4; ++t) {
    f16x4 hv;
#pragma unroll
    for (int rr = 0; rr < 4; ++rr) {
      hv[rr] = (_Float16)acc[t][rr];
      s1p[rr] += acc[t][rr] * a1v[t];
      s2p[rr] += acc[t][rr] * a2v[t];
    }
    // hT[bh][d = t*16+c][n = nb + w*16 + q*4 .. +3]  (4 consecutive n -> 8B store)
    *(f16x4*)&hT[((size_t)(bh * 64 + t * 16 + c)) * NN + nb + w * 16 + q * 4] = hv;
  }
#pragma unroll
  for (int rr = 0; rr < 4; ++rr) {
    float s1 = s1p[rr], s2 = s2p[rr];
#pragma unroll
    for (int off = 8; off; off >>= 1) {
      s1 += __shfl_xor(s1, off);
      s2 += __shfl_xor(s2, off);
    }
    if (c == 0) {
      int n = nb + w * 16 + q * 4 + rr;
      s1_ws[(size_t)bh * NN + n] = s1;
      s2_ws[(size_t)bh * NN + n] = s2;
    }
  }
}

// ---------------------------------------------------------------------------
// Kernel B: attention, two-pass (exact row max, no online rescale) + fp16 MFMA
// Block = (ntile: 64 n-rows, bh). 4 waves; wave w owns score rows w*16..+15
// and output d-slice w*16..+15 (so B-frags are loaded exactly once per block).
// Pass1: read adj once, pack mask bits into LDS, lane-local row max.
// Pass2: p = exp(e - M) final -> fp16 P-tile in LDS (double-buffered,
//        1 barrier/chunk) -> MFMA against B-frags read straight from hT (L2).
// ---------------------------------------------------------------------------
__global__ __launch_bounds__(256) void attn(const _Float16* __restrict__ hT,
                                            const float* __restrict__ s1_ws,
                                            const float* __restrict__ s2_ws,
                                            const int* __restrict__ adj,
                                            float* __restrict__ out) {
  __shared__ float s2_all[NN];               // 4KB
  __shared__ float s1_blk[64];
  __shared__ unsigned short mskT[64][64];    // [w*16+chunk][m-lane] bit r = row w*16+r
  __shared__ _Float16 pt[2][64][88];         // P tiles, 176B stride (16B-mult)
  __shared__ float L_lds[64];
  const int tid = threadIdx.x, lane = tid & 63, w = tid >> 6;
  const int c = lane & 15, q = lane >> 4;
  const int ntile = blockIdx.x, bh = blockIdx.y;
  const int b = bh >> 2, head = bh & 3;
  const int n0 = ntile * 64;

  {
    float4 v = *(const float4*)&s2_ws[(size_t)bh * NN + tid * 4];
    *(float4*)&s2_all[tid * 4] = v;
    if (tid < 64) s1_blk[tid] = s1_ws[(size_t)bh * NN + n0 + tid];
  }
  __syncthreads();

  float S1[16];
#pragma unroll
  for (int r = 0; r < 16; ++r) S1[r] = s1_blk[w * 16 + r];

  // ---- pass 1: adj -> bitmask, exact row max ----
  float M[16];
#pragma unroll
  for (int r = 0; r < 16; ++r) M[r] = -1e30f;
  const int* adjp = adj + ((size_t)(b * NN + n0 + w * 16)) * NN + lane;
  for (int ch = 0; ch < 16; ++ch) {
    int av[16];
#pragma unroll
    for (int r = 0; r < 16; ++r) av[r] = adjp[(size_t)r * NN + ch * 64];
    float s2v = s2_all[ch * 64 + lane];
    unsigned bits = 0;
#pragma unroll
    for (int r = 0; r < 16; ++r) {
      float e = S1[r] + s2v;
      e = fmaxf(e, 0.2f * e);  // leaky_relu
      bits |= (av[r] != 0) ? (1u << r) : 0u;
      e = (av[r] != 0) ? e : -1e30f;
      M[r] = fmaxf(M[r], e);
    }
    mskT[w * 16 + ch][lane] = (unsigned short)bits;
  }
#pragma unroll
  for (int r = 0; r < 16; ++r) {
    float m = M[r];
#pragma unroll
    for (int off = 32; off; off >>= 1) m = fmaxf(m, __shfl_xor(m, off));
    M[r] = m;
  }

  // ---- pass 2: p -> fp16 LDS tile, MFMA accumulate ----
  float Lp[16];
#pragma unroll
  for (int r = 0; r < 16; ++r) Lp[r] = 0.f;
  f32x4 acc[4];
#pragma unroll
  for (int t = 0; t < 4; ++t) acc[t] = (f32x4){0.f, 0.f, 0.f, 0.f};
  // B-frag pointer: lane reads hT[bh][d = w*16 + c][m = m0 + q*8 .. +7]
  const _Float16* bptr = hT + (size_t)bh * 64 * NN + (size_t)(w * 16 + c) * NN + q * 8;

  for (int ch = 0; ch < 16; ++ch) {
    const int m0 = ch * 64;
    const int buf = ch & 1;
    float s2v = s2_all[m0 + lane];
    unsigned mbits = mskT[w * 16 + ch][lane];
#pragma unroll
    for (int r = 0; r < 16; ++r) {
      float e = S1[r] + s2v;
      e = fmaxf(e, 0.2f * e);
      e = ((mbits >> r) & 1) ? e : -1e30f;
      float p = __expf(e - M[r]);
      Lp[r] += p;
      pt[buf][w * 16 + r][lane] = (_Float16)p;
    }
    f16x8 bf0 = *(const f16x8*)(bptr + m0);
    f16x8 bf1 = *(const f16x8*)(bptr + m0 + 32);
    __syncthreads();  // publish pt[buf]; double-buffer makes 1 barrier/chunk safe
#pragma unroll
    for (int t = 0; t < 4; ++t) {
      f16x8 af0 = *(const f16x8*)&pt[buf][t * 16 + c][q * 8];
      f16x8 af1 = *(const f16x8*)&pt[buf][t * 16 + c][32 + q * 8];
      acc[t] = __builtin_amdgcn_mfma_f32_16x16x32_f16(af0, bf0, acc[t], 0, 0, 0);
      acc[t] = __builtin_amdgcn_mfma_f32_16x16x32_f16(af1, bf1, acc[t], 0, 0, 0);
    }
  }

  // ---- epilogue: L reduce + store ----
  float lv = 0.f;
#pragma unroll
  for (int r = 0; r < 16; ++r) {
    float s = Lp[r];
#pragma unroll
    for (int off = 32; off; off >>= 1) s += __shfl_xor(s, off);
    lv = (lane == r) ? s : lv;
  }
  if (lane < 16) L_lds[w * 16 + lane] = lv;
  __syncthreads();
#pragma unroll
  for (int t = 0; t < 4; ++t) {
#pragma unroll
    for (int rr = 0; rr < 4; ++rr) {
      int nloc = t * 16 + q * 4 + rr;  // D row (n); D col = c -> d = w*16 + c
      out[((size_t)(b * NN + n0 + nloc)) * FOUT + head * 64 + w * 16 + c] =
          acc[t][rr] / L_lds[nloc];
    }
  }
}

extern "C" void kernel_launch(void* const* d_in, const int* in_sizes, int n_in,
                              void* d_out, int out_size, void* d_ws, size_t ws_size,
                              hipStream_t stream) {
  const float* x = (const float*)d_in[0];
  const int* adj = (const int*)d_in[1];
  const float* W = (const float*)d_in[2];
  const float* a = (const float*)d_in[3];
  float* out = (float*)d_out;

  _Float16* hT = (_Float16*)d_ws;  // [32][64][1024] fp16 = 4MB
  float* s1_ws = (float*)((char*)d_ws + (size_t)BB * H * HD * NN * sizeof(_Float16));
  float* s2_ws = s1_ws + (size_t)BB * H * NN;

  gemm_xw<<<dim3(128, 4), 256, 0, stream>>>(x, W, a, hT, s1_ws, s2_ws);
  attn<<<dim3(16, 32), 256, 0, stream>>>(hT, s1_ws, s2_ws, adj, out);
}